// Round 4
// baseline (1005.077 us; speedup 1.0000x reference)
//
#include <hip/hip_runtime.h>
#include <cstddef>

// Problem dims
#define CI_  64
#define CO_  256
#define DD_  31
#define HH_  96
#define WW_  96
#define HW_  (HH_*WW_)      // 9216
#define DHW_ (DD_*HW_)      // 285696
#define EPSV 1e-5f

// Fused tiling: block = 1 h-row x 16 w x all 256 co x all d (quads of 4)
// Halo plane LDS layout (halves): [row3][k2][cig4][col18][ci8]
#define P_COL 8
#define P_CIG 144           // 18*8
#define P_K   576           // 4*144
#define P_ROW 1152          // 2*576
#define P_SZ  3456          // 3*1152 halves per plane (6912 B)
#define NSLOT 6
#define HALO_N (NSLOT*P_SZ) // 20736 halves
// Gate LDS layout (halves): [l4][c64][sp16x4g + pad4] -> c stride 68
#define G_C   68
#define G_L   4352          // 64*68
#define GATE_N (4*G_L)      // 17408 halves
#define LDS_HALVES (HALO_N + GATE_N)   // 38144 halves = 76288 B

typedef _Float16 half8   __attribute__((ext_vector_type(8)));
typedef _Float16 half4v  __attribute__((ext_vector_type(4)));
typedef float    float4v __attribute__((ext_vector_type(4)));

// -------- weight repack: w[co][ci][kd][kh][kw] fp32 -> wr[t][co][ci] fp16 --------
__global__ __launch_bounds__(256) void repack_w_k(const float* __restrict__ w,
                                                  _Float16* __restrict__ wr) {
  int idx = blockIdx.x * 256 + threadIdx.x;   // 27*256*64
  if (idx >= 27 * 256 * 64) return;
  int ci = idx & 63;
  int co = (idx >> 6) & 255;
  int t  = idx >> 14;
  wr[idx] = (_Float16)w[co * 1728 + ci * 27 + t];
}

// -------- fused conv3d + BN + act + SRU recurrence --------
// grid 576 = 96 hti x 6 wti. block 256 = 4 waves; wave = gate group.
__global__ __launch_bounds__(256, 2) void fused_k(
    const float* __restrict__ x, const _Float16* __restrict__ wr,
    const float* __restrict__ gamma, const float* __restrict__ beta,
    const float* __restrict__ mean, const float* __restrict__ var,
    float* __restrict__ out)
{
  __shared__ _Float16 lds[LDS_HALVES];
  _Float16* gl = lds + HALO_N;

  const int wti = blockIdx.x % 6;
  const int hti = blockIdx.x / 6;
  const int h0  = hti, w0 = wti * 16;

  const int tid  = threadIdx.x;
  const int lane = tid & 63;
  const int wave = __builtin_amdgcn_readfirstlane(tid >> 6);
  const int lw   = lane & 15;
  const int quad = lane >> 4;

  // BN constants for this wave's 64 co (co = wave*64 + j*16 + lw)
  float sj[4], bj[4];
#pragma unroll
  for (int j = 0; j < 4; j++) {
    int co = wave * 64 + j * 16 + lw;
    sj[j] = gamma[co] * rsqrtf(var[co] + EPSV);
    bj[j] = fmaf(-mean[co], sj[j], beta[co]);
  }
  const bool istanh = (wave == 0) || (wave == 3);

  // recurrence state: thread owns (c = (tid>>4)*4 + cc, sp = tid&15)
  const int sp = tid & 15;
  const int c0 = (tid >> 4) * 4;
  float Cst[4];
#pragma unroll
  for (int cc = 0; cc < 4; cc++) Cst[cc] = 0.f;

  // ---- stage planes -1..4 into slots 5,0,1,2,3,4 ----
  {
    for (int i = tid; i < 6 * 864; i += 256) {
      int pl  = i / 864;
      int rem = i - pl * 864;
      int row = rem / 288;
      int r2  = rem - row * 288;
      int cg  = r2 / 18;
      int col = r2 - cg * 18;
      int p   = pl - 1;
      int slot = (p < 0) ? 5 : p;
      int gh = h0 - 1 + row, gw = w0 - 1 + col;
      half4v hv;
      if ((unsigned)p < (unsigned)DD_ && (unsigned)gh < (unsigned)HH_ &&
          (unsigned)gw < (unsigned)WW_) {
        const float* xp = x + (size_t)(cg * 4) * DHW_ + (size_t)p * HW_ + gh * WW_ + gw;
#pragma unroll
        for (int jj = 0; jj < 4; jj++) hv[jj] = (_Float16)xp[(size_t)jj * DHW_];
      } else {
#pragma unroll
        for (int jj = 0; jj < 4; jj++) hv[jj] = (_Float16)0.f;
      }
      int a = slot * P_SZ + row * P_ROW + (cg >> 3) * P_K + ((cg >> 1) & 3) * P_CIG +
              col * P_COL + (cg & 1) * 4;
      *(half4v*)(lds + a) = hv;
    }
  }
  __syncthreads();

  // ---- d-quad loop: s=0..7, d = 4s+l ----
#pragma unroll 1
  for (int s = 0; s < 8; s++) {
    const int base = (4 * s + 5) % 6;   // slot of plane 4s-1

    float4v acc[4][4];
#pragma unroll
    for (int l = 0; l < 4; l++)
#pragma unroll
      for (int j = 0; j < 4; j++) acc[l][j] = (float4v)0.f;

    // K loop: 9 (kh,kw) x 2 k-chunks x 3 kd
#pragma unroll 1
    for (int khw = 0; khw < 9; khw++) {
      const int kh = khw / 3;
      const int kw = khw - kh * 3;
#pragma unroll
      for (int k = 0; k < 2; k++) {
        half8 af[6];
#pragma unroll
        for (int u = 0; u < 6; u++) {
          int sl = base + u; if (sl >= 6) sl -= 6;
          af[u] = *(const half8*)(lds + sl * P_SZ + kh * P_ROW + k * P_K +
                                  quad * P_CIG + (lw + kw) * P_COL);
        }
#pragma unroll
        for (int kd = 0; kd < 3; kd++) {
          const int t = kd * 9 + khw;
          const _Float16* bp = wr + ((size_t)(t * 256 + wave * 64 + lw) << 6) +
                               k * 32 + quad * 8;
          half8 bf[4];
#pragma unroll
          for (int j = 0; j < 4; j++) bf[j] = *(const half8*)(bp + (size_t)j * 1024);
#pragma unroll
          for (int l = 0; l < 4; l++)
#pragma unroll
            for (int j = 0; j < 4; j++)
              acc[l][j] = __builtin_amdgcn_mfma_f32_16x16x32_f16(af[l + kd], bf[j],
                                                                 acc[l][j], 0, 0, 0);
        }
      }
    }

    // ---- BN + activation -> gate LDS [l][c][sp*4 + g] ----
#pragma unroll
    for (int l = 0; l < 4; l++)
#pragma unroll
      for (int j = 0; j < 4; j++) {
#pragma unroll
        for (int reg = 0; reg < 4; reg++) {
          float v = fmaf(acc[l][j][reg], sj[j], bj[j]);
          float a;
          if (istanh) {
            float tt = __expf(-2.f * fabsf(v));
            float r  = (1.f - tt) * __builtin_amdgcn_rcpf(1.f + tt);
            a = copysignf(r, v);
          } else {
            a = __builtin_amdgcn_rcpf(1.f + __expf(-v));
          }
          gl[l * G_L + (j * 16 + lw) * G_C + (quad * 4 + reg) * 4 + wave] = (_Float16)a;
        }
      }
    __syncthreads();

    // ---- stage next step's 4 planes (overlaps with update; disjoint LDS) ----
    if (s < 7) {
      for (int i = tid; i < 4 * 864; i += 256) {
        int pl  = i / 864;
        int rem = i - pl * 864;
        int row = rem / 288;
        int r2  = rem - row * 288;
        int cg  = r2 / 18;
        int col = r2 - cg * 18;
        int p    = 4 * s + 5 + pl;
        int slot = p % 6;
        int gh = h0 - 1 + row, gw = w0 - 1 + col;
        half4v hv;
        if ((unsigned)p < (unsigned)DD_ && (unsigned)gh < (unsigned)HH_ &&
            (unsigned)gw < (unsigned)WW_) {
          const float* xp = x + (size_t)(cg * 4) * DHW_ + (size_t)p * HW_ + gh * WW_ + gw;
#pragma unroll
          for (int jj = 0; jj < 4; jj++) hv[jj] = (_Float16)xp[(size_t)jj * DHW_];
        } else {
#pragma unroll
          for (int jj = 0; jj < 4; jj++) hv[jj] = (_Float16)0.f;
        }
        int a = slot * P_SZ + row * P_ROW + (cg >> 3) * P_K + ((cg >> 1) & 3) * P_CIG +
                col * P_COL + (cg & 1) * 4;
        *(half4v*)(lds + a) = hv;
      }
    }

    // ---- recurrence update + output store ----
#pragma unroll
    for (int l = 0; l < 4; l++) {
      const int d = 4 * s + l;
      if (d < DD_) {
#pragma unroll
        for (int cc = 0; cc < 4; cc++) {
          const int c = c0 + cc;
          half4v gv = *(const half4v*)(gl + l * G_L + c * G_C + sp * 4);
          float wx = (float)gv[0], f = (float)gv[1], r = (float)gv[2], xx = (float)gv[3];
          float Cv = (d == 0) ? (1.f - f) : fmaf(f, Cst[cc] - wx, wx);
          Cst[cc] = Cv;
          out[(size_t)c * DHW_ + (size_t)d * HW_ + h0 * WW_ + w0 + sp] =
              fmaf(r, Cv - xx, xx);
        }
      }
    }
    __syncthreads();
  }
}

extern "C" void kernel_launch(void* const* d_in, const int* in_sizes, int n_in,
                              void* d_out, int out_size, void* d_ws, size_t ws_size,
                              hipStream_t stream) {
  const float* x     = (const float*)d_in[0];
  const float* w     = (const float*)d_in[1];
  const float* gamma = (const float*)d_in[2];
  const float* beta  = (const float*)d_in[3];
  const float* mean  = (const float*)d_in[4];
  const float* var   = (const float*)d_in[5];
  float* out = (float*)d_out;

  _Float16* wr = (_Float16*)d_ws;   // 27*256*64 fp16 = 884736 B

  repack_w_k<<<(27 * 256 * 64 + 255) / 256, 256, 0, stream>>>(w, wr);
  fused_k<<<576, 256, 0, stream>>>(x, wr, gamma, beta, mean, var, out);
}

// Round 5
// 724.593 us; speedup vs baseline: 1.3871x; 1.3871x over previous
//
#include <hip/hip_runtime.h>
#include <cstddef>

// Problem dims
#define CI_  64
#define CO_  256
#define DD_  31
#define HH_  96
#define WW_  96
#define HW_  (HH_*WW_)      // 9216
#define DHW_ (DD_*HW_)      // 285696
#define EPSV 1e-5f

// Conv tile: M=64 (4h x 16w) x N=256 (4 waves x 64co), one d per block.
// LDS halo layout (halves): [dd3][row6][cig4][col18][ci8]
#define S_COL 8
#define S_CIG 144           // 18*8
#define S_ROW 576           // 4*144
#define S_DD  3456          // 6*576
#define XH_N  10368         // 3*3456 halves = 20736 B

#define NTILE 144           // 24 hti * 6 wti per d-plane
#define GSP   64            // spatial elems per block gate region per co

typedef _Float16 half8   __attribute__((ext_vector_type(8)));
typedef _Float16 half4v  __attribute__((ext_vector_type(4)));
typedef float    float4v __attribute__((ext_vector_type(4)));

// -------- weight repack: w[co][ci][kd][kh][kw] fp32 -> wr[t][co][ci] fp16 --------
__global__ __launch_bounds__(256) void repack_w_k(const float* __restrict__ w,
                                                  _Float16* __restrict__ wr) {
  int idx = blockIdx.x * 256 + threadIdx.x;   // 27*256*64
  if (idx >= 27 * 256 * 64) return;
  int ci = idx & 63;
  int co = (idx >> 6) & 255;
  int t  = idx >> 14;
  wr[idx] = (_Float16)w[co * 1728 + ci * 27 + t];
}

// -------- conv3d (implicit GEMM, f16 MFMA) + BN + act -> block-private gates ----
// grid: x = 144 tiles (hti*6+wti), y = 31 (d). block 256 = 4 waves.
// wave = gate group (64 co); all waves share M=64 spatial.
__global__ __launch_bounds__(256, 4) void conv_mfma_k(
    const float* __restrict__ x, const _Float16* __restrict__ wr,
    const float* __restrict__ gamma, const float* __restrict__ beta,
    const float* __restrict__ mean, const float* __restrict__ var,
    _Float16* __restrict__ gates)
{
  __shared__ _Float16 xh[XH_N];

  const int bx  = blockIdx.x;        // 0..143
  const int d   = blockIdx.y;
  const int wti = bx % 6;
  const int hti = bx / 6;
  const int h0  = hti * 4, w0 = wti * 16;

  const int tid  = threadIdx.x;
  const int lane = tid & 63;
  const int wave = __builtin_amdgcn_readfirstlane(tid >> 6);
  const int lw   = lane & 15;        // A: m(spatial)  B: n(co)
  const int quad = lane >> 4;        // k-group (8 ci)

  float4v acc[4][4];
#pragma unroll
  for (int m = 0; m < 4; m++)
#pragma unroll
    for (int j = 0; j < 4; j++) acc[m][j] = (float4v)0.f;

  for (int cc = 0; cc < CI_; cc += 32) {
    __syncthreads();
    // ---- stage halo: 4 cig x 3 dd x 6 row x 18 col tasks, 8 ci per task ----
    for (int i = tid; i < 1296; i += 256) {
      int cig = i / 324;
      int r   = i - cig * 324;
      int dd  = r / 108;
      int r2  = r - dd * 108;
      int row = r2 / 18;
      int col = r2 - row * 18;
      int gd = d + dd - 1, gh = h0 + row - 1, gw = w0 + col - 1;
      half8 hv;
      if ((unsigned)gd < (unsigned)DD_ && (unsigned)gh < (unsigned)HH_ &&
          (unsigned)gw < (unsigned)WW_) {
        const float* xp = x + (size_t)(cc + cig * 8) * DHW_ + gd * HW_ + gh * WW_ + gw;
#pragma unroll
        for (int jj = 0; jj < 8; jj++) hv[jj] = (_Float16)xp[(size_t)jj * DHW_];
      } else {
#pragma unroll
        for (int jj = 0; jj < 8; jj++) hv[jj] = (_Float16)0.f;
      }
      *(half8*)(xh + dd * S_DD + row * S_ROW + cig * S_CIG + col * S_COL) = hv;
    }
    __syncthreads();

    // ---- K loop: 27 taps, k=32 per MFMA covers the ci chunk ----
#pragma unroll 1
    for (int t = 0; t < 27; t++) {
      const int kd = t / 9;
      const int rm = t - kd * 9;
      const int kh = rm / 3;
      const int kw = rm - kh * 3;
      const _Float16* bp = wr + ((size_t)(t * 256 + wave * 64 + lw) << 6) + cc + quad * 8;
      half8 bf[4];
#pragma unroll
      for (int j = 0; j < 4; j++) bf[j] = *(const half8*)(bp + (size_t)j * 1024);
      const int abase = kd * S_DD + kh * S_ROW + quad * S_CIG + (lw + kw) * S_COL;
      half8 af[4];
#pragma unroll
      for (int m = 0; m < 4; m++)
        af[m] = *(const half8*)(xh + abase + m * S_ROW);
#pragma unroll
      for (int m = 0; m < 4; m++)
#pragma unroll
        for (int j = 0; j < 4; j++)
          acc[m][j] = __builtin_amdgcn_mfma_f32_16x16x32_f16(af[m], bf[j], acc[m][j], 0, 0, 0);
    }
  }

  // ---- epilogue: BN + activation, block-private gate region ----
  // gates[((d*144+bx)*256 + co)*64 + sp], sp = h_local*16 + w_local
  _Float16* gb = gates + ((size_t)(d * NTILE + bx) * 256) * GSP;
  const bool istanh = (wave == 0) || (wave == 3);
#pragma unroll
  for (int j = 0; j < 4; j++) {
    const int co = wave * 64 + j * 16 + lw;
    const float s  = gamma[co] * rsqrtf(var[co] + EPSV);
    const float bb = fmaf(-mean[co], s, beta[co]);
#pragma unroll
    for (int m = 0; m < 4; m++) {
      half4v hv;
#pragma unroll
      for (int reg = 0; reg < 4; reg++) {
        float v = fmaf(acc[m][j][reg], s, bb);
        float a;
        if (istanh) {
          float tt = __expf(-2.f * fabsf(v));
          float r  = (1.f - tt) * __builtin_amdgcn_rcpf(1.f + tt);
          a = copysignf(r, v);
        } else {
          a = __builtin_amdgcn_rcpf(1.f + __expf(-v));
        }
        hv[reg] = (_Float16)a;
      }
      // D row index = quad*4+reg -> w_local; m = h_local
      *(half4v*)(gb + (size_t)co * GSP + m * 16 + quad * 4) = hv;
    }
  }
}

// -------- SRU recurrence over d; thread per (c, bx, ml) --------
__global__ __launch_bounds__(256) void recurrence_k(const _Float16* __restrict__ gates,
                                                    float* __restrict__ out) {
  const int idx = blockIdx.x * 256 + threadIdx.x;   // 64*144*64 = 589824
  const int ml  = idx & 63;
  const int t2  = idx >> 6;          // c*144 + bx
  const int c   = t2 / NTILE;
  const int bx  = t2 - c * NTILE;
  const int hti = bx / 6, wti = bx - hti * 6;
  const int h = hti * 4 + (ml >> 4);
  const int w = wti * 16 + (ml & 15);

  const size_t DSTR = (size_t)NTILE * 256 * GSP;    // per-d gate stride
  const _Float16* g0 = gates + (size_t)bx * 256 * GSP + ml;
  float* op = out + (size_t)c * DHW_ + h * WW_ + w;

  float C = 0.f;
#pragma unroll 1
  for (int d = 0; d < DD_; d++) {
    const _Float16* g = g0 + (size_t)d * DSTR;
    float wx = (float)g[(size_t)c * GSP];
    float f  = (float)g[(size_t)(c + 64) * GSP];
    float r  = (float)g[(size_t)(c + 128) * GSP];
    float xx = (float)g[(size_t)(c + 192) * GSP];
    C = (d == 0) ? (1.f - f) : fmaf(f, C - wx, wx);
    op[(size_t)d * HW_] = fmaf(r, C - xx, xx);
  }
}

extern "C" void kernel_launch(void* const* d_in, const int* in_sizes, int n_in,
                              void* d_out, int out_size, void* d_ws, size_t ws_size,
                              hipStream_t stream) {
  const float* x     = (const float*)d_in[0];
  const float* w     = (const float*)d_in[1];
  const float* gamma = (const float*)d_in[2];
  const float* beta  = (const float*)d_in[3];
  const float* mean  = (const float*)d_in[4];
  const float* var   = (const float*)d_in[5];
  float* out = (float*)d_out;

  // ws: [wr: 27*256*64 fp16 = 884736 B][align 256][gates: 31*144*256*64 fp16]
  _Float16* wr    = (_Float16*)d_ws;
  _Float16* gates = (_Float16*)((char*)d_ws + ((27 * 256 * 64 * 2 + 255) & ~255));

  repack_w_k<<<(27 * 256 * 64 + 255) / 256, 256, 0, stream>>>(w, wr);

  dim3 gconv(NTILE, DD_);
  conv_mfma_k<<<gconv, 256, 0, stream>>>(x, wr, gamma, beta, mean, var, gates);

  recurrence_k<<<(64 * NTILE * GSP) / 256, 256, 0, stream>>>(gates, out);
}